// Round 4
// baseline (1239.637 us; speedup 1.0000x reference)
//
#include <hip/hip_runtime.h>
#include <math.h>

#define B_ 4
#define H_ 16
#define S_ 1024
#define R_ 512
#define BQ 64
#define BK 64
#define NTHREADS 512
#define NKS 16   // K steps in mm1: 512 / 32

typedef unsigned short u16;
typedef unsigned int   u32;
typedef short bf16x8 __attribute__((ext_vector_type(8)));
typedef float f32x4  __attribute__((ext_vector_type(4)));

__device__ inline u16 f2bf(float x) {
    union { float f; u32 u; } v; v.f = x;
    return (u16)((v.u + 0x7fffu + ((v.u >> 16) & 1u)) >> 16);
}
__device__ inline u32 pack2(float a, float b) {
    return (u32)f2bf(a) | ((u32)f2bf(b) << 16);
}

#define MFMA16(a, b, c) __builtin_amdgcn_mfma_f32_16x16x32_bf16(a, b, c, 0, 0, 0)

// async global->LDS, 16B per lane. LDS dest must be wave-uniform (HW adds lane*16).
__device__ inline void gload16(const void* g, void* l) {
    __builtin_amdgcn_global_load_lds(
        (const __attribute__((address_space(1))) void*)g,
        (__attribute__((address_space(3))) void*)l,
        16, 0, 0);
}

// ---------------------------------------------------------------------------
// Prep kernel (verified in round 1): ckv f32 -> bf16, two layouts:
//   ckv_bf [b][k][r]  16B chunks XOR-swizzled within each 128B span by (k&7)
//                     -> LINEAR global_load_lds yields conflict-free LDS tiles.
//   ckvT   [b][r][k]  plain transpose (consumed directly from global by mm2).
// ---------------------------------------------------------------------------
__global__ __launch_bounds__(256)
void mla_prep_kernel(const float* __restrict__ ckv,
                     u16* __restrict__ ckv_bf,
                     u16* __restrict__ ckvT)
{
    const int tid = threadIdx.x;
    const int k0 = blockIdx.x * 64;
    const int r0 = blockIdx.y * 64;
    const int b  = blockIdx.z;

    __shared__ u16 sT[64][72];   // [r_local][k_local], padded rows

    const float* src = ckv + ((size_t)b * S_ + k0) * R_ + r0;
    u16* obf = ckv_bf + ((size_t)b * S_ + k0) * R_ + r0;

    #pragma unroll
    for (int i = 0; i < 2; ++i) {
        int idx = tid + i * 256;          // 0..511
        int kk  = idx >> 3;               // 0..63 local k row
        int c8  = idx & 7;                // dest 16B chunk within 128B span
        int csrc = c8 ^ (kk & 7);         // source chunk (XOR swizzle)
        const float* p = src + (size_t)kk * R_ + csrc * 8;
        float4 f0 = *(const float4*)p;
        float4 f1 = *(const float4*)(p + 4);
        u32 w0 = pack2(f0.x, f0.y), w1 = pack2(f0.z, f0.w);
        u32 w2 = pack2(f1.x, f1.y), w3 = pack2(f1.z, f1.w);
        u32* dst = (u32*)(obf + (size_t)kk * R_ + c8 * 8);
        dst[0] = w0; dst[1] = w1; dst[2] = w2; dst[3] = w3;
        u16 e[8] = {(u16)w0,(u16)(w0>>16),(u16)w1,(u16)(w1>>16),
                    (u16)w2,(u16)(w2>>16),(u16)w3,(u16)(w3>>16)};
        #pragma unroll
        for (int j = 0; j < 8; ++j) sT[csrc * 8 + j][kk] = e[j];
    }
    __syncthreads();

    u16* obT = ckvT + (size_t)b * R_ * S_;
    #pragma unroll
    for (int i = 0; i < 2; ++i) {
        int idx = tid + i * 256;          // 0..511
        int rr = idx >> 3;                // 0..63 local r row
        int kc = idx & 7;                 // 16B chunk along k
        const u16* s = &sT[rr][kc * 8];
        u32* dd = (u32*)(obT + (size_t)(r0 + rr) * S_ + k0 + kc * 8);
        dd[0] = (u32)s[0] | ((u32)s[1] << 16);
        dd[1] = (u32)s[2] | ((u32)s[3] << 16);
        dd[2] = (u32)s[4] | ((u32)s[5] << 16);
        dd[3] = (u32)s[6] | ((u32)s[7] << 16);
    }
}

// ---------------------------------------------------------------------------
// Main kernel: BK=64, softmax pipelined one tile behind mm1 -> ONE barrier
// per iteration. 8 waves: qg = wv>>1 (16 q-rows), ktg = wv&1 (32-kv half).
// sPP/sMeta/sAlpha DOUBLE-buffered: reuse distance spans one barrier
// (writer at kt+2 is pre-barrier(kt+2); reader at kt is post-barrier(kt);
// barrier(kt+1) separates them). LDS 150,016 B (1 block/CU).
// mm2 B-frags loaded from global ckvT (L2/L3-hot) into regs at iter top.
// waves_per_eu(2,2): 256-VGPR tier, no spills (tripwire: WRITE_SIZE).
// s_setprio(1) around MFMA clusters (T5): 2 waves/SIMD at different phases.
// ---------------------------------------------------------------------------
__global__ __attribute__((amdgpu_waves_per_eu(2, 2)))
__launch_bounds__(NTHREADS)
void mla_attn_kernel(const float* __restrict__ qn,
                     const float* __restrict__ rope,
                     const int*   __restrict__ mask,
                     const int*   __restrict__ cmaskp,
                     const u16*   __restrict__ ckv_bf,
                     const u16*   __restrict__ ckvT,
                     float*       __restrict__ out)
{
    const int tid  = threadIdx.x;
    const int lane = tid & 63;
    const int wv   = tid >> 6;     // wave 0..7
    const int l15  = lane & 15;
    const int lq   = lane >> 4;    // quad 0..3
    const int qg   = wv >> 1;      // q-group 0..3 (16 rows each)
    const int ktg  = wv & 1;       // kv-half 0..1 (32 cols each)

    // heavy (high-qt, causal) blocks first
    const int qt = (int)gridDim.x - 1 - (int)blockIdx.x;
    const int h  = blockIdx.y;
    const int b  = blockIdx.z;
    const int q0 = qt * BQ;

    const int cflag = cmaskp[0];

    // LDS: 131072 + 16384 + 2048 + 512 = 150,016 B (1 block/CU)
    __shared__ __align__(16) u16   sCKV[2][BK][R_];   // swizzled rows, 1024B each
    __shared__ __align__(16) u16   sPP[2][BQ][BK];    // P, 128B rows, XOR (row&7)<<4
    __shared__ __align__(16) float sMeta[2][BQ][4];   // [0]=vm ktg0 [1]=vm ktg1
    __shared__ __align__(16) f32x4 sAlpha[2][16];     // alpha packed per 4-row group

    // ---- Q fragments in registers: rows [qg*16, +16), full K=512 ----
    bf16x8 aq[NKS];
    {
        const float* qrow = qn + ((size_t)((b * H_ + h) * S_ + q0 + qg * 16 + l15)) * R_;
        #pragma unroll
        for (int s = 0; s < NKS; ++s) {
            const float* p = qrow + 32 * s + lq * 8;
            float4 f0 = *(const float4*)p;
            float4 f1 = *(const float4*)(p + 4);
            union { u32 u[4]; bf16x8 v; } cv;
            cv.u[0] = pack2(f0.x, f0.y); cv.u[1] = pack2(f0.z, f0.w);
            cv.u[2] = pack2(f1.x, f1.y); cv.u[3] = pack2(f1.z, f1.w);
            aq[s] = cv.v;
        }
    }

    f32x4 acc[4][4];
    #pragma unroll
    for (int i = 0; i < 4; ++i)
        #pragma unroll
        for (int j = 0; j < 4; ++j)
            acc[i][j] = (f32x4){0.f, 0.f, 0.f, 0.f};

    float m_run[4], l_run[4];
    #pragma unroll
    for (int r = 0; r < 4; ++r) { m_run[r] = -INFINITY; l_run[r] = 0.0f; }

    const u16*   ckvb  = ckv_bf + (size_t)b * S_ * R_;
    const u16*   ckvTb = ckvT   + (size_t)b * R_ * S_;
    const float* ropeb = rope + ((size_t)(b * H_ + h)) * S_ * S_;
    const int*   maskb = mask + b * S_;

    const int nkt = cflag ? (qt + 1) : (S_ / BK);
    const float SCALE = 0.07216878364870323f;   // 1/sqrt(64+128)
    const int rowg0 = q0 + qg * 16 + 4 * lq;

    // pipelined state
    float rp[2][4], rpn[2][4];     // rope for current / next mm1 tile
    int   mkv[2], mkvn[2];
    float scp[2][4];               // scores of tile kt-1 (pre-softmax-finish)
    float vmp[4];                  // own-half row max of tile kt-1
    bf16x8 bfr[4][2];              // mm2 B-frags for tile kt-1 (from global)

    // ---- prologue: stage tile 0, rope/mask(0) ----
    {
        char* lA = (char*)&sCKV[0][0][0] + wv * 1024;
        const char* gA = (const char*)ckvb;
        #pragma unroll
        for (int rd = 0; rd < 8; ++rd) {
            u32 o = (u32)(rd * 8192 + wv * 1024 + (lane & 63) * 16);
            gload16(gA + o, lA + rd * 8192);
        }
        const float* rb2 = ropeb + (size_t)rowg0 * S_ + ktg * 32 + l15;
        #pragma unroll
        for (int reg = 0; reg < 4; ++reg) {
            rp[0][reg] = rb2[(size_t)reg * S_];
            rp[1][reg] = rb2[(size_t)reg * S_ + 16];
        }
        mkv[0] = maskb[ktg * 32 + l15];
        mkv[1] = maskb[ktg * 32 + 16 + l15];
    }
    __syncthreads();   // tile 0 staged (vmcnt drained)

    for (int kt = 0; kt <= nkt; ++kt) {
        const int d   = kt & 1;
        const int pbc = kt & 1;        // buffer for vm(kt)
        const int pbm = pbc ^ 1;       // buffer for tile kt-1 (P, alpha, vm)

        // ---- top: issue async stage(kt+1), rope(kt+1), bfr(kt-1) ----
        if (kt + 1 < nkt) {
            const char* gA = (const char*)ckvb + (size_t)(kt + 1) * (BK * R_ * 2);
            char* lA = (char*)&sCKV[d ^ 1][0][0] + wv * 1024;
            #pragma unroll
            for (int rd = 0; rd < 8; ++rd) {
                u32 o = (u32)(rd * 8192 + wv * 1024 + (lane & 63) * 16);
                gload16(gA + o, lA + rd * 8192);
            }
            const int k0n = (kt + 1) * BK;
            const float* rb2 = ropeb + (size_t)rowg0 * S_ + k0n + ktg * 32 + l15;
            #pragma unroll
            for (int reg = 0; reg < 4; ++reg) {
                rpn[0][reg] = rb2[(size_t)reg * S_];
                rpn[1][reg] = rb2[(size_t)reg * S_ + 16];
            }
            mkvn[0] = maskb[k0n + ktg * 32 + l15];
            mkvn[1] = maskb[k0n + ktg * 32 + 16 + l15];
        }
        if (kt >= 1) {
            const u16* tb = ckvTb + (size_t)(wv * 64 + l15) * S_ + (kt - 1) * BK + lq * 8;
            #pragma unroll
            for (int ni = 0; ni < 4; ++ni)
                #pragma unroll
                for (int ks = 0; ks < 2; ++ks)
                    bfr[ni][ks] = *(const bf16x8*)(tb + (size_t)ni * 16 * S_ + ks * 32);
        }

        // ---- mm1(kt) + own-half row max + publish vm ----
        float scf[2][4], vm[4];
        if (kt < nkt) {
            f32x4 sc00 = {0.f,0.f,0.f,0.f}, sc01 = {0.f,0.f,0.f,0.f};
            f32x4 sc10 = {0.f,0.f,0.f,0.f}, sc11 = {0.f,0.f,0.f,0.f};
            const char* base = (const char*)&sCKV[d][0][0];
            const u32 row0b = (u32)(ktg * 32 + l15) * 1024;
            const u32 row1b = row0b + 16 * 1024;
            const u32 swz = ((u32)(l15 & 7)) << 4;
            __builtin_amdgcn_s_setprio(1);
            #pragma unroll
            for (int s = 0; s < NKS; s += 2) {
                u32 c0 = ((u32)(64 * s)      + (u32)(16 * lq)) ^ swz;
                u32 c1 = ((u32)(64 * s + 64) + (u32)(16 * lq)) ^ swz;
                bf16x8 b00 = *(const bf16x8*)(base + row0b + c0);
                bf16x8 b10 = *(const bf16x8*)(base + row1b + c0);
                bf16x8 b01 = *(const bf16x8*)(base + row0b + c1);
                bf16x8 b11 = *(const bf16x8*)(base + row1b + c1);
                sc00 = MFMA16(aq[s],     b00, sc00);
                sc10 = MFMA16(aq[s],     b10, sc10);
                sc01 = MFMA16(aq[s + 1], b01, sc01);
                sc11 = MFMA16(aq[s + 1], b11, sc11);
            }
            __builtin_amdgcn_s_setprio(0);
            const int colg0 = kt * BK + ktg * 32 + l15;
            #pragma unroll
            for (int reg = 0; reg < 4; ++reg) {
                float v0 = (sc00[reg] + sc01[reg] + rp[0][reg]) * SCALE;
                float v1 = (sc10[reg] + sc11[reg] + rp[1][reg]) * SCALE;
                if (mkv[0]) v0 = -INFINITY;
                if (mkv[1]) v1 = -INFINITY;
                if (cflag && colg0      > rowg0 + reg) v0 = -INFINITY;
                if (cflag && colg0 + 16 > rowg0 + reg) v1 = -INFINITY;
                scf[0][reg] = v0; scf[1][reg] = v1;
                vm[reg] = fmaxf(v0, v1);
            }
            #pragma unroll
            for (int m = 1; m <= 8; m <<= 1)
                #pragma unroll
                for (int reg = 0; reg < 4; ++reg)
                    vm[reg] = fmaxf(vm[reg], __shfl_xor(vm[reg], m));
            if (l15 == 0) {
                #pragma unroll
                for (int reg = 0; reg < 4; ++reg)
                    sMeta[pbc][qg * 16 + 4 * lq + reg][ktg] = vm[reg];
            }
        }

        // ---- softmax finish (kt-1): combine halves, write P + alpha ----
        if (kt >= 1) {
            float alpha[4], pv0[4], pv1[4], rs[4];
            #pragma unroll
            for (int reg = 0; reg < 4; ++reg) {
                float pm = sMeta[pbm][qg * 16 + 4 * lq + reg][ktg ^ 1];
                float mn = fmaxf(m_run[reg], fmaxf(vmp[reg], pm));
                if (mn == -INFINITY) {
                    alpha[reg] = 1.0f; pv0[reg] = 0.0f; pv1[reg] = 0.0f;
                } else {
                    alpha[reg] = __expf(m_run[reg] - mn);
                    pv0[reg]   = __expf(scp[0][reg] - mn);
                    pv1[reg]   = __expf(scp[1][reg] - mn);
                }
                m_run[reg] = mn;
                rs[reg] = pv0[reg] + pv1[reg];
            }
            #pragma unroll
            for (int m = 1; m <= 8; m <<= 1)
                #pragma unroll
                for (int reg = 0; reg < 4; ++reg)
                    rs[reg] += __shfl_xor(rs[reg], m);
            char* pbase = (char*)&sPP[pbm][0][0];
            #pragma unroll
            for (int reg = 0; reg < 4; ++reg) {
                l_run[reg] = l_run[reg] * alpha[reg] + rs[reg];
                const u32 row = (u32)(qg * 16 + 4 * lq + reg);
                const u32 rswz = (row & 7) << 4;
                u32 w0 = ((u32)(ktg * 64      + 2 * l15)) ^ rswz;
                u32 w1 = ((u32)(ktg * 64 + 32 + 2 * l15)) ^ rswz;
                *(u16*)(pbase + row * 128 + w0) = f2bf(pv0[reg]);
                *(u16*)(pbase + row * 128 + w1) = f2bf(pv1[reg]);
            }
            if (ktg == 0 && l15 == 0) {
                f32x4 av = {alpha[0], alpha[1], alpha[2], alpha[3]};
                sAlpha[pbm][qg * 4 + lq] = av;
            }
        }

        // carry pipeline state
        if (kt < nkt) {
            #pragma unroll
            for (int reg = 0; reg < 4; ++reg) {
                vmp[reg] = vm[reg];
                scp[0][reg] = scf[0][reg]; scp[1][reg] = scf[1][reg];
                rp[0][reg] = rpn[0][reg];  rp[1][reg] = rpn[1][reg];
            }
            mkv[0] = mkvn[0]; mkv[1] = mkvn[1];
        }

        __syncthreads();   // the ONE barrier: vm(kt), P(kt-1), alpha(kt-1)
                           // visible; stage(kt+1) + bfr(kt-1) drained

        // ---- mm2(kt-1): O = O*alpha + P . CKV ----
        if (kt >= 1) {
            f32x4 alr[4];
            #pragma unroll
            for (int mi = 0; mi < 4; ++mi)
                alr[mi] = sAlpha[pbm][mi * 4 + lq];
            #pragma unroll
            for (int mi = 0; mi < 4; ++mi)
                #pragma unroll
                for (int ni = 0; ni < 4; ++ni)
                    #pragma unroll
                    for (int reg = 0; reg < 4; ++reg)
                        acc[mi][ni][reg] *= alr[mi][reg];

            bf16x8 af[4][2];
            const char* pbase = (const char*)&sPP[pbm][0][0];
            const u32 rswz = ((u32)(l15 & 7)) << 4;
            #pragma unroll
            for (int mi = 0; mi < 4; ++mi) {
                const u32 rb = (u32)(mi * 16 + l15) * 128;
                af[mi][0] = *(const bf16x8*)(pbase + rb + (((u32)(16 * lq))      ^ rswz));
                af[mi][1] = *(const bf16x8*)(pbase + rb + (((u32)(64 + 16 * lq)) ^ rswz));
            }
            __builtin_amdgcn_s_setprio(1);
            #pragma unroll
            for (int mi = 0; mi < 4; ++mi)
                #pragma unroll
                for (int ni = 0; ni < 4; ++ni) {
                    acc[mi][ni] = MFMA16(af[mi][0], bfr[ni][0], acc[mi][ni]);
                    acc[mi][ni] = MFMA16(af[mi][1], bfr[ni][1], acc[mi][ni]);
                }
            __builtin_amdgcn_s_setprio(0);
        }
    }

    // ---- epilogue: exchange per-row l across kv-half waves, then O / l ----
    if (l15 == 0) {
        #pragma unroll
        for (int reg = 0; reg < 4; ++reg)
            sMeta[0][qg * 16 + 4 * lq + reg][ktg] = l_run[reg];
    }
    __syncthreads();

    float linv[4][4];
    #pragma unroll
    for (int mi = 0; mi < 4; ++mi)
        #pragma unroll
        for (int reg = 0; reg < 4; ++reg) {
            int row = mi * 16 + 4 * lq + reg;
            float lt = sMeta[0][row][0] + sMeta[0][row][1];
            linv[mi][reg] = 1.0f / lt;
        }

    float* ob = out + ((size_t)((b * H_ + h) * S_ + q0)) * R_;
    #pragma unroll
    for (int mi = 0; mi < 4; ++mi)
        #pragma unroll
        for (int ni = 0; ni < 4; ++ni)
            #pragma unroll
            for (int reg = 0; reg < 4; ++reg)
                ob[(size_t)(mi * 16 + 4 * lq + reg) * R_ + wv * 64 + ni * 16 + l15]
                    = acc[mi][ni][reg] * linv[mi][reg];
}

extern "C" void kernel_launch(void* const* d_in, const int* in_sizes, int n_in,
                              void* d_out, int out_size, void* d_ws, size_t ws_size,
                              hipStream_t stream)
{
    (void)in_sizes; (void)n_in; (void)out_size; (void)ws_size;
    const float* qn   = (const float*)d_in[0];
    const float* ckv  = (const float*)d_in[1];
    const float* rope = (const float*)d_in[2];
    const int*   mask = (const int*)d_in[3];
    const int*   cm   = (const int*)d_in[4];
    float* out = (float*)d_out;

    // workspace: ckv_bf (4MB, swizzled [b][k][r]) + ckvT (4MB, [b][r][k])
    u16* ckv_bf = (u16*)d_ws;
    u16* ckvT   = ckv_bf + (size_t)B_ * S_ * R_;

    hipLaunchKernelGGL(mla_prep_kernel, dim3(S_ / 64, R_ / 64, B_), dim3(256),
                       0, stream, ckv, ckv_bf, ckvT);
    hipLaunchKernelGGL(mla_attn_kernel, dim3(S_ / BQ, H_, B_), dim3(NTHREADS),
                       0, stream, qn, rope, mask, cm, ckv_bf, ckvT, out);
}